// Round 1
// baseline (687.025 us; speedup 1.0000x reference)
//
#include <hip/hip_runtime.h>
#include <hip/hip_bf16.h>

// ActLayer: out[b,o] = sum_{i,f} norm(sin(w_f x[b,i] + p_f)) * beta[f,o] * lamb[i,o] + bias[o]
// Restructured as C[B,O] = A[B, K=F*I] @ W[K,O] with
//   A[b,(f,i)] = sin(w_f x[b,i] + p_f)         (computed on the fly, never materialized)
//   W[(f,i),o] = beta[f,o]*r_f * lamb[i,o]     (staged per f-step from registers/LDS)
// plus per-column constant c[o] = bias[o] - (sum_f beta r m)_o * (sum_i lamb)_o.
//
// B=8192, I=512, F=64, O=512.  BM=64, BN=128, BK=64 (one f per K-step).
// 256 threads = 4 waves (2x2 wave grid, 32x64 per wave, mfma 16x16x32 bf16).
// Grid = 128*4 = 512 blocks -> 2 blocks/CU. LDS ~48KB.

#define TB 256

typedef __attribute__((ext_vector_type(8))) short short8;
typedef __attribute__((ext_vector_type(4))) float floatx4;
typedef __attribute__((ext_vector_type(4))) unsigned int uintx4;

__device__ __forceinline__ unsigned pk_bf16(float a, float b) {
    __hip_bfloat162 h = __float22bfloat162_rn(make_float2(a, b));
    union { __hip_bfloat162 h2; unsigned u; } cv; cv.h2 = h; return cv.u;
}
__device__ __forceinline__ unsigned short f_to_bf16u(float v) {
    union { __hip_bfloat16 h; unsigned short u; } cv;
    cv.h = __float2bfloat16(v);
    return cv.u;
}
__device__ __forceinline__ float bf16u_to_f(unsigned short v) {
    union { unsigned u; float f; } cv; cv.u = ((unsigned)v) << 16; return cv.f;
}

__global__ __launch_bounds__(TB, 2)
void actlayer_kernel(const float* __restrict__ x,
                     const float* __restrict__ freqs,
                     const float* __restrict__ phases,
                     const float* __restrict__ beta,
                     const float* __restrict__ lamb,
                     const float* __restrict__ bias,
                     float* __restrict__ out)
{
    constexpr int I = 512, F = 64, O = 512;
    constexpr int BM = 64, BN = 128;
    const int t  = threadIdx.x;
    const int bx = blockIdx.x;
    const int bn = bx & 3;            // 0..3
    const int bm = bx >> 2;           // 0..127
    const int n0 = bn * BN;
    const int m0 = bm * BM;

    __shared__ __align__(16) unsigned short A_sh[BM][72];     // [m][k] bf16 sin tile
    __shared__ __align__(16) unsigned short Bm_sh[BN][72];    // [n][k] bf16 W tile
    __shared__ unsigned short betaRT_sh[BN][72];              // [n][f] bf16 beta*r
    __shared__ float wrev_sh[F], prev_sh[F], r_sh[F], m_sh[F];
    __shared__ float c_sh[BN];
    __shared__ float slp_sh[2][BN];

    // ---- prologue: per-f normalization constants ----
    if (t < F) {
        float wq = freqs[t];
        float ph = phases[t];
        float e1 = expf(-0.5f * wq * wq);
        float mean = e1 * sinf(ph);
        float e2 = expf(-2.0f * wq * wq);
        float var = 0.5f - 0.5f * e2 * cosf(2.0f * ph) - mean * mean;
        float r = 1.0f / sqrtf(1e-3f + var);
        wrev_sh[t] = wq * 0.15915494309189535f;   // /2pi -> revolutions for v_sin
        prev_sh[t] = ph * 0.15915494309189535f;
        r_sh[t] = r;
        m_sh[t] = mean;
    }
    // sl[n] = sum_i lamb[i][n0+n], split over 2 halves of i
    {
        int n = t & 127, half = t >> 7;
        float s = 0.f;
        const float* lp = lamb + (size_t)(half * 256) * O + n0 + n;
        #pragma unroll 8
        for (int i = 0; i < 256; ++i) s += lp[(size_t)i * O];
        slp_sh[half][n] = s;
    }
    __syncthreads();
    // betaRT[n][f] = beta[f][n0+n] * r_f  (bf16)
    #pragma unroll
    for (int j = 0; j < 32; ++j) {
        int e = t + TB * j;
        int f = e >> 7;       // 0..63
        int n = e & 127;
        float bv = beta[f * O + n0 + n] * r_sh[f];
        betaRT_sh[n][f] = f_to_bf16u(bv);
    }
    __syncthreads();
    if (t < BN) {
        float sb = 0.f;
        #pragma unroll
        for (int f = 0; f < F; ++f) sb += bf16u_to_f(betaRT_sh[t][f]) * m_sh[f];
        c_sh[t] = bias[n0 + t] - sb * (slp_sh[0][t] + slp_sh[1][t]);
    }
    // (visibility of c_sh is guaranteed by the barriers inside the main loop)

    // ---- staging geometry: runs of 8 consecutive k ----
    const int kr = t & 7;          // k-run index: k = kr*8 .. +8
    const int r0 = t >> 3;         // 0..31

    // ---- wave geometry ----
    const int lane = t & 63;
    const int wid  = t >> 6;
    const int wr = wid >> 1;       // 0..1 : m 32-row half
    const int wc = wid & 1;        // 0..1 : n 64-col half
    const int l15 = lane & 15;
    const int quad = lane >> 4;

    floatx4 acc[2][4];
    #pragma unroll
    for (int a = 0; a < 2; ++a)
        #pragma unroll
        for (int b = 0; b < 4; ++b)
            acc[a][b] = (floatx4){0.f, 0.f, 0.f, 0.f};

    for (int it = 0; it < 8; ++it) {
        const int i0 = it * 64;
        // x tile -> registers (reused across all 64 f): 2 runs of 8
        float xr[2][8];
        #pragma unroll
        for (int j = 0; j < 2; ++j) {
            int m = r0 + 32 * j;
            const float* xp = x + (size_t)(m0 + m) * I + i0 + kr * 8;
            float4 v0 = *(const float4*)(xp);
            float4 v1 = *(const float4*)(xp + 4);
            xr[j][0]=v0.x; xr[j][1]=v0.y; xr[j][2]=v0.z; xr[j][3]=v0.w;
            xr[j][4]=v1.x; xr[j][5]=v1.y; xr[j][6]=v1.z; xr[j][7]=v1.w;
        }
        // lamb tile -> registers: 4 runs of 8 (column reads, L2-resident)
        float lr[4][8];
        #pragma unroll
        for (int j = 0; j < 4; ++j) {
            int n = r0 + 32 * j;
            const float* lp = lamb + (size_t)(i0 + kr * 8) * O + n0 + n;
            #pragma unroll
            for (int jj = 0; jj < 8; ++jj) lr[j][jj] = lp[(size_t)jj * O];
        }
        #pragma unroll 1
        for (int f = 0; f < F; ++f) {
            float wfr = wrev_sh[f], pfr = prev_sh[f];
            // stage A: sin(w_f * x + p_f) -> bf16
            #pragma unroll
            for (int j = 0; j < 2; ++j) {
                int m = r0 + 32 * j;
                float s[8];
                #pragma unroll
                for (int jj = 0; jj < 8; ++jj) {
                    float arg = __builtin_amdgcn_fractf(fmaf(xr[j][jj], wfr, pfr));
                    s[jj] = __builtin_amdgcn_sinf(arg);
                }
                uintx4 w4;
                w4.x = pk_bf16(s[0], s[1]); w4.y = pk_bf16(s[2], s[3]);
                w4.z = pk_bf16(s[4], s[5]); w4.w = pk_bf16(s[6], s[7]);
                *(uintx4*)&A_sh[m][kr * 8] = w4;
            }
            // stage B: betaR[f][n] * lamb[k][n] -> bf16
            #pragma unroll
            for (int j = 0; j < 4; ++j) {
                int n = r0 + 32 * j;
                float br = bf16u_to_f(betaRT_sh[n][f]);
                uintx4 w4;
                w4.x = pk_bf16(lr[j][0] * br, lr[j][1] * br);
                w4.y = pk_bf16(lr[j][2] * br, lr[j][3] * br);
                w4.z = pk_bf16(lr[j][4] * br, lr[j][5] * br);
                w4.w = pk_bf16(lr[j][6] * br, lr[j][7] * br);
                *(uintx4*)&Bm_sh[n][kr * 8] = w4;
            }
            __syncthreads();
            // MFMA: 2 k-chunks of 32, 2x4 fragment grid per wave
            #pragma unroll
            for (int kk = 0; kk < 2; ++kk) {
                short8 af[2], bfr[4];
                #pragma unroll
                for (int mt = 0; mt < 2; ++mt)
                    af[mt] = *(const short8*)&A_sh[wr*32 + mt*16 + l15][kk*32 + quad*8];
                #pragma unroll
                for (int nt = 0; nt < 4; ++nt)
                    bfr[nt] = *(const short8*)&Bm_sh[wc*64 + nt*16 + l15][kk*32 + quad*8];
                #pragma unroll
                for (int mt = 0; mt < 2; ++mt)
                    #pragma unroll
                    for (int nt = 0; nt < 4; ++nt)
                        acc[mt][nt] = __builtin_amdgcn_mfma_f32_16x16x32_bf16(
                            af[mt], bfr[nt], acc[mt][nt], 0, 0, 0);
            }
            __syncthreads();
        }
    }

    // ---- epilogue: add per-column constant, store fp32 ----
    #pragma unroll
    for (int mt = 0; mt < 2; ++mt) {
        int gm = m0 + wr*32 + mt*16 + quad*4;
        #pragma unroll
        for (int nt = 0; nt < 4; ++nt) {
            int gn = n0 + wc*64 + nt*16 + l15;
            float cv = c_sh[wc*64 + nt*16 + l15];
            #pragma unroll
            for (int rg = 0; rg < 4; ++rg) {
                out[(size_t)(gm + rg) * O + gn] = acc[mt][nt][rg] + cv;
            }
        }
    }
}

extern "C" void kernel_launch(void* const* d_in, const int* in_sizes, int n_in,
                              void* d_out, int out_size, void* d_ws, size_t ws_size,
                              hipStream_t stream) {
    const float* x      = (const float*)d_in[0];
    const float* freqs  = (const float*)d_in[1];
    const float* phases = (const float*)d_in[2];
    const float* beta   = (const float*)d_in[3];
    const float* lamb   = (const float*)d_in[4];
    const float* bias   = (const float*)d_in[5];
    float* out = (float*)d_out;

    dim3 grid(512);   // (8192/64) m-blocks * (512/128) n-blocks
    dim3 block(TB);
    hipLaunchKernelGGL(actlayer_kernel, grid, block, 0, stream,
                       x, freqs, phases, beta, lamb, bias, out);
}

// Round 2
// 510.497 us; speedup vs baseline: 1.3458x; 1.3458x over previous
//
#include <hip/hip_runtime.h>
#include <hip/hip_bf16.h>

// ActLayer: out[b,o] = sum_{i,f} norm(sin(w_f x[b,i] + p_f)) * beta[f,o] * lamb[i,o] + bias[o]
//
// Round-2 structure: per f-step compute S_f = A_f (sin tile, on-the-fly) @ Lambda
// (f-INVARIANT bf16 tile, staged once per i-tile and held in register fragments),
// then fold the per-(f,o) scale into the accumulator: out += betaR[f,o] (.) S_f.
// This removes all per-f B-tile staging. A (sin) tile is double-buffered ->
// ONE barrier per f, sin(f+1) overlaps ds_read/MFMA of f.
//
// B=8192, I=512, F=64, O=512.  BM=64, BN=128, i-chunk 64 (one f per K-step).
// 256 threads = 4 waves (2x2 wave grid, 32x64/wave, mfma 16x16x32 bf16).
// Grid = 512 blocks -> 2 blocks/CU. LDS = 64000 B (fits 2/CU).

#define TB 256

typedef __attribute__((ext_vector_type(8))) short short8;
typedef __attribute__((ext_vector_type(4))) float floatx4;
typedef __attribute__((ext_vector_type(4))) unsigned int uintx4;
typedef __attribute__((ext_vector_type(4))) unsigned short ushort4t;

__device__ __forceinline__ unsigned pk_bf16(float a, float b) {
    __hip_bfloat162 h = __float22bfloat162_rn(make_float2(a, b));
    union { __hip_bfloat162 h2; unsigned u; } cv; cv.h2 = h; return cv.u;
}
__device__ __forceinline__ unsigned short f_to_bf16u(float v) {
    union { __hip_bfloat16 h; unsigned short u; } cv;
    cv.h = __float2bfloat16(v);
    return cv.u;
}
__device__ __forceinline__ float bf16u_to_f(unsigned short v) {
    union { unsigned u; float f; } cv; cv.u = ((unsigned)v) << 16; return cv.f;
}

__global__ __launch_bounds__(TB, 2)
void actlayer_kernel(const float* __restrict__ x,
                     const float* __restrict__ freqs,
                     const float* __restrict__ phases,
                     const float* __restrict__ beta,
                     const float* __restrict__ lamb,
                     const float* __restrict__ bias,
                     float* __restrict__ out)
{
    constexpr int I = 512, F = 64, O = 512;
    constexpr int BM = 64, BN = 128;
    const int t  = threadIdx.x;
    const int bx = blockIdx.x;
    const int bn = bx & 3;            // 0..3
    const int bm = bx >> 2;           // 0..127
    const int n0 = bn * BN;
    const int m0 = bm * BM;

    // pad 72 shorts = 144 B rows: 16B-aligned for b128 everywhere
    __shared__ __align__(16) unsigned short A_sh[2][BM][72];   // sin tile, double-buffered
    __shared__ __align__(16) unsigned short L_sh[BN][72];      // lambda tile (bf16), per i-tile
    __shared__ __align__(16) unsigned short brP_sh[F][16][12]; // betaR bf16: [f][c=o%16][w=o/16]
    __shared__ float wrev_sh[F], prev_sh[F], r_sh[F], m_sh[F];
    __shared__ float c_sh[BN];
    __shared__ float slp_sh[2][BN];

    // ---- prologue: per-f normalization constants ----
    if (t < F) {
        float wq = freqs[t];
        float ph = phases[t];
        float e1 = expf(-0.5f * wq * wq);
        float mean = e1 * sinf(ph);
        float e2 = expf(-2.0f * wq * wq);
        float var = 0.5f - 0.5f * e2 * cosf(2.0f * ph) - mean * mean;
        float r = 1.0f / sqrtf(1e-3f + var);
        wrev_sh[t] = wq * 0.15915494309189535f;   // /2pi -> revolutions for v_sin
        prev_sh[t] = ph * 0.15915494309189535f;
        r_sh[t] = r;
        m_sh[t] = mean;
    }
    // sl[n] = sum_i lamb[i][n0+n], split over 2 halves of i
    {
        int n = t & 127, half = t >> 7;
        float s = 0.f;
        const float* lp = lamb + (size_t)(half * 256) * O + n0 + n;
        #pragma unroll 8
        for (int i = 0; i < 256; ++i) s += lp[(size_t)i * O];
        slp_sh[half][n] = s;
    }
    __syncthreads();
    // brP[f][c][w] = beta[f][n0 + w*16 + c] * r_f   (bf16)
    #pragma unroll
    for (int j = 0; j < 32; ++j) {
        int e = t + TB * j;          // 0..8191
        int f = e >> 7;              // 0..63
        int rem = e & 127;
        int w = rem >> 4;            // 0..7
        int c = rem & 15;
        float bv = beta[f * O + n0 + w * 16 + c] * r_sh[f];
        brP_sh[f][c][w] = f_to_bf16u(bv);
    }
    __syncthreads();
    if (t < BN) {
        int c = t & 15, w = t >> 4;
        float sb = 0.f;
        #pragma unroll
        for (int f = 0; f < F; ++f) sb += bf16u_to_f(brP_sh[f][c][w]) * m_sh[f];
        c_sh[t] = bias[n0 + t] - sb * (slp_sh[0][t] + slp_sh[1][t]);
    }

    // ---- staging geometry: runs of 8 consecutive k ----
    const int kr = t & 7;          // k-run: k = kr*8 .. +8
    const int r0 = t >> 3;         // 0..31

    // ---- wave geometry ----
    const int lane = t & 63;
    const int wid  = t >> 6;
    const int wr = wid >> 1;       // m 32-row half
    const int wc = wid & 1;        // n 64-col half
    const int l15 = lane & 15;
    const int quad = lane >> 4;

    floatx4 oacc[2][4];
    #pragma unroll
    for (int a = 0; a < 2; ++a)
        #pragma unroll
        for (int b = 0; b < 4; ++b)
            oacc[a][b] = (floatx4){0.f, 0.f, 0.f, 0.f};

    const floatx4 zero4 = (floatx4){0.f, 0.f, 0.f, 0.f};

    #pragma unroll 1
    for (int it = 0; it < 8; ++it) {
        const int i0 = it * 64;
        // x tile -> registers (reused across all 64 f)
        float xr[2][8];
        #pragma unroll
        for (int j = 0; j < 2; ++j) {
            int m = r0 + 32 * j;
            const float* xp = x + (size_t)(m0 + m) * I + i0 + kr * 8;
            float4 v0 = *(const float4*)(xp);
            float4 v1 = *(const float4*)(xp + 4);
            xr[j][0]=v0.x; xr[j][1]=v0.y; xr[j][2]=v0.z; xr[j][3]=v0.w;
            xr[j][4]=v1.x; xr[j][5]=v1.y; xr[j][6]=v1.z; xr[j][7]=v1.w;
        }
        // lambda tile -> LDS (bf16), once per i-tile.
        // thread: one column n, 32 k values (coalesced across lanes for each k).
        {
            int n  = t & 127;
            int kh = t >> 7;           // 0..1
            const float* lp = lamb + (size_t)(i0 + kh * 32) * O + n0 + n;
            float v[32];
            #pragma unroll
            for (int k = 0; k < 32; ++k) v[k] = lp[(size_t)k * O];
            #pragma unroll
            for (int rr = 0; rr < 4; ++rr) {
                uintx4 w4;
                w4.x = pk_bf16(v[rr*8+0], v[rr*8+1]);
                w4.y = pk_bf16(v[rr*8+2], v[rr*8+3]);
                w4.z = pk_bf16(v[rr*8+4], v[rr*8+5]);
                w4.w = pk_bf16(v[rr*8+6], v[rr*8+7]);
                *(uintx4*)&L_sh[n][kh * 32 + rr * 8] = w4;
            }
        }
        // stage A for f=0 into buffer 0
        {
            float wfr = wrev_sh[0], pfr = prev_sh[0];
            #pragma unroll
            for (int j = 0; j < 2; ++j) {
                int m = r0 + 32 * j;
                float s[8];
                #pragma unroll
                for (int jj = 0; jj < 8; ++jj) {
                    float arg = __builtin_amdgcn_fractf(fmaf(xr[j][jj], wfr, pfr));
                    s[jj] = __builtin_amdgcn_sinf(arg);
                }
                uintx4 w4;
                w4.x = pk_bf16(s[0], s[1]); w4.y = pk_bf16(s[2], s[3]);
                w4.z = pk_bf16(s[4], s[5]); w4.w = pk_bf16(s[6], s[7]);
                *(uintx4*)&A_sh[0][m][kr * 8] = w4;
            }
        }
        __syncthreads();

        // lambda fragments (f-invariant within this i-tile)
        short8 lf[2][4];   // [kk][nt]
        #pragma unroll
        for (int kk = 0; kk < 2; ++kk)
            #pragma unroll
            for (int nt = 0; nt < 4; ++nt)
                lf[kk][nt] = *(const short8*)&L_sh[wc*64 + nt*16 + l15][kk*32 + quad*8];

        #pragma unroll 2
        for (int f = 0; f < F; ++f) {
            const int cur = f & 1;
            // A fragments for f
            short8 af[2][2];   // [mt][kk]
            #pragma unroll
            for (int mt = 0; mt < 2; ++mt)
                #pragma unroll
                for (int kk = 0; kk < 2; ++kk)
                    af[mt][kk] = *(const short8*)&A_sh[cur][wr*32 + mt*16 + l15][kk*32 + quad*8];
            // betaR values for f (4 columns per lane), bf16 b64 read
            ushort4t bru = *(const ushort4t*)&brP_sh[f][l15][wc * 4];
            float br[4];
            #pragma unroll
            for (int nt = 0; nt < 4; ++nt) br[nt] = bf16u_to_f(bru[nt]);

            // overlap: stage sin tile for f+1 into the other buffer
            if (f < F - 1) {
                float wfr = wrev_sh[f + 1], pfr = prev_sh[f + 1];
                #pragma unroll
                for (int j = 0; j < 2; ++j) {
                    int m = r0 + 32 * j;
                    float s[8];
                    #pragma unroll
                    for (int jj = 0; jj < 8; ++jj) {
                        float arg = __builtin_amdgcn_fractf(fmaf(xr[j][jj], wfr, pfr));
                        s[jj] = __builtin_amdgcn_sinf(arg);
                    }
                    uintx4 w4;
                    w4.x = pk_bf16(s[0], s[1]); w4.y = pk_bf16(s[2], s[3]);
                    w4.z = pk_bf16(s[4], s[5]); w4.w = pk_bf16(s[6], s[7]);
                    *(uintx4*)&A_sh[cur ^ 1][m][kr * 8] = w4;
                }
            }

            // S_f = A_f @ Lambda ; out += betaR (.) S_f
            #pragma unroll
            for (int mt = 0; mt < 2; ++mt) {
                #pragma unroll
                for (int nt = 0; nt < 4; ++nt) {
                    floatx4 s = __builtin_amdgcn_mfma_f32_16x16x32_bf16(
                        af[mt][0], lf[0][nt], zero4, 0, 0, 0);
                    s = __builtin_amdgcn_mfma_f32_16x16x32_bf16(
                        af[mt][1], lf[1][nt], s, 0, 0, 0);
                    oacc[mt][nt] += br[nt] * s;
                }
            }
            __syncthreads();
        }
    }

    // ---- epilogue: add per-column constant, store fp32 ----
    #pragma unroll
    for (int mt = 0; mt < 2; ++mt) {
        int gm = m0 + wr*32 + mt*16 + quad*4;
        #pragma unroll
        for (int nt = 0; nt < 4; ++nt) {
            int gn = n0 + wc*64 + nt*16 + l15;
            float cv = c_sh[wc*64 + nt*16 + l15];
            #pragma unroll
            for (int rg = 0; rg < 4; ++rg) {
                out[(size_t)(gm + rg) * O + gn] = oacc[mt][nt][rg] + cv;
            }
        }
    }
}

extern "C" void kernel_launch(void* const* d_in, const int* in_sizes, int n_in,
                              void* d_out, int out_size, void* d_ws, size_t ws_size,
                              hipStream_t stream) {
    const float* x      = (const float*)d_in[0];
    const float* freqs  = (const float*)d_in[1];
    const float* phases = (const float*)d_in[2];
    const float* beta   = (const float*)d_in[3];
    const float* lamb   = (const float*)d_in[4];
    const float* bias   = (const float*)d_in[5];
    float* out = (float*)d_out;

    dim3 grid(512);   // (8192/64) m-blocks * (512/128) n-blocks
    dim3 block(TB);
    hipLaunchKernelGGL(actlayer_kernel, grid, block, 0, stream,
                       x, freqs, phases, beta, lamb, bias, out);
}